// Round 3
// baseline (882.669 us; speedup 1.0000x reference)
//
#include <hip/hip_runtime.h>
#include <math.h>

typedef float v4f __attribute__((ext_vector_type(4)));

// Problem constants: hidden [2,32,1024] f32, encoder_outputs [32,4096,1024] f32,
// mask [32,4096] int. Outputs: context [32,1024] f32 ++ attn [32,4096] f32.
#define B_ 32
#define S_ 4096
#define H_ 1024
#define NBLK 32                                // blocks per batch in pass 1
#define ROWS_PER_BLOCK (S_ / NBLK)             // 128
#define NWAVE 4
#define ROWS_PER_WAVE (ROWS_PER_BLOCK / NWAVE) // 32
#define CHUNK 2                                // rows per chunk
#define NCHUNK (ROWS_PER_WAVE / CHUNK)         // 16
#define NEG_INF_ -1.0e9f

// Pass 1: single pass over encoder_outputs with double-buffered register
// prefetch: chunk k+1's 8 nontemporal 16B loads are issued BEFORE chunk k's
// compute, so s_waitcnt vmcnt(8) keeps memory in flight during the
// dot/shuffle/softmax phase. Mask handled via one coalesced load + __ballot.
__global__ __launch_bounds__(256, 4) void attn_pass1(
    const float* __restrict__ hidden,   // [2,B,H] — use layer 1 (last)
    const float* __restrict__ enc,      // [B,S,H]
    const int*   __restrict__ mask,     // [B,S]
    float* __restrict__ scores,         // raw scores -> attn slot of d_out [B,S]
    float* __restrict__ part_ctx,       // ws: [B*NBLK, H]
    float* __restrict__ part_ml)        // ws: [B*NBLK, 2] = (M, L)
{
    const int blk  = blockIdx.x;        // 0 .. B*NBLK-1
    const int b    = blk >> 5;          // / NBLK
    const int cb   = blk & 31;          // % NBLK
    const int tid  = threadIdx.x;
    const int wave = tid >> 6;
    const int lane = tid & 63;

    // h fragment: lane holds elems {4L..4L+3, 256+4L.., 512+4L.., 768+4L..}
    const v4f* h4 = (const v4f*)(hidden + (size_t)(B_ + b) * H_); // layer -1
    const v4f hf0 = h4[lane];
    const v4f hf1 = h4[lane + 64];
    const v4f hf2 = h4[lane + 128];
    const v4f hf3 = h4[lane + 192];

    const int    row0  = cb * ROWS_PER_BLOCK + wave * ROWS_PER_WAVE;
    const float* encb  = enc  + (size_t)b * S_ * H_;
    const int*   maskb = mask + (size_t)b * S_;

    // wave-uniform mask bits: bit r = mask of row row0+r  (r < 32)
    const int mval = (lane < ROWS_PER_WAVE) ? maskb[row0 + lane] : 0;
    const unsigned long long mbits = __ballot(mval != 0);

    float m = -INFINITY;
    float l = 0.0f;
    v4f c0 = (v4f)0.0f, c1 = (v4f)0.0f, c2 = (v4f)0.0f, c3 = (v4f)0.0f;
    float myscore = 0.0f;               // lane r (r<32) keeps row row0+r's score

    v4f buf[2][CHUNK][4];

    auto load_chunk = [&](int k, int slot) {
        #pragma unroll
        for (int c = 0; c < CHUNK; ++c) {
            const v4f* row4 = (const v4f*)(encb + (size_t)(row0 + k * CHUNK + c) * H_);
            buf[slot][c][0] = __builtin_nontemporal_load(&row4[lane]);
            buf[slot][c][1] = __builtin_nontemporal_load(&row4[lane + 64]);
            buf[slot][c][2] = __builtin_nontemporal_load(&row4[lane + 128]);
            buf[slot][c][3] = __builtin_nontemporal_load(&row4[lane + 192]);
        }
    };

    load_chunk(0, 0);

    #pragma unroll
    for (int k = 0; k < NCHUNK; ++k) {
        const int cur = k & 1;
        if (k + 1 < NCHUNK) load_chunk(k + 1, cur ^ 1);   // prefetch next

        // ---- partial dots ----
        float pd[CHUNK];
        #pragma unroll
        for (int c = 0; c < CHUNK; ++c) {
            const v4f p0 = buf[cur][c][0] * hf0;
            const v4f p1 = buf[cur][c][1] * hf1;
            const v4f p2 = buf[cur][c][2] * hf2;
            const v4f p3 = buf[cur][c][3] * hf3;
            const v4f ps = p0 + p1 + p2 + p3;
            pd[c] = ps.x + ps.y + ps.z + ps.w;
        }

        // ---- butterfly reduce, 2 independent values per stage ----
        #pragma unroll
        for (int off = 32; off >= 1; off >>= 1) {
            #pragma unroll
            for (int c = 0; c < CHUNK; ++c)
                pd[c] += __shfl_xor(pd[c], off, 64);
        }

        // ---- mask -> scores (wave-uniform bit test) ----
        float sc[CHUNK];
        #pragma unroll
        for (int c = 0; c < CHUNK; ++c) {
            sc[c] = ((mbits >> (k * CHUNK + c)) & 1ULL) ? pd[c] : NEG_INF_;
            if (lane == k * CHUNK + c) myscore = sc[c];
        }

        // ---- online softmax update (once per chunk) ----
        const float cmax  = fmaxf(sc[0], sc[1]);
        const float newm  = fmaxf(m, cmax);
        const float scale = __expf(m - newm);      // exp(-inf)=0 handles init
        float p[CHUNK];
        #pragma unroll
        for (int c = 0; c < CHUNK; ++c) p[c] = __expf(sc[c] - newm);
        l = l * scale + p[0] + p[1];

        c0 = c0 * scale + p[0] * buf[cur][0][0] + p[1] * buf[cur][1][0];
        c1 = c1 * scale + p[0] * buf[cur][0][1] + p[1] * buf[cur][1][1];
        c2 = c2 * scale + p[0] * buf[cur][0][2] + p[1] * buf[cur][1][2];
        c3 = c3 * scale + p[0] * buf[cur][0][3] + p[1] * buf[cur][1][3];
        m = newm;
    }

    // coalesced raw-score store: lane r (r<32) holds score of row row0+r
    if (lane < ROWS_PER_WAVE)
        scores[(size_t)b * S_ + row0 + lane] = myscore;

    // combine the 4 waves of this block in LDS
    __shared__ v4f lds_ctx[NWAVE][H_ / 4];   // 16 KB
    __shared__ float lds_m[NWAVE];
    __shared__ float lds_l[NWAVE];
    lds_ctx[wave][lane]       = c0;
    lds_ctx[wave][lane + 64]  = c1;
    lds_ctx[wave][lane + 128] = c2;
    lds_ctx[wave][lane + 192] = c3;
    if (lane == 0) { lds_m[wave] = m; lds_l[wave] = l; }
    __syncthreads();

    const float M  = fmaxf(fmaxf(lds_m[0], lds_m[1]), fmaxf(lds_m[2], lds_m[3]));
    const float w0 = __expf(lds_m[0] - M);
    const float w1 = __expf(lds_m[1] - M);
    const float w2 = __expf(lds_m[2] - M);
    const float w3 = __expf(lds_m[3] - M);

    const v4f o = lds_ctx[0][tid] * w0 + lds_ctx[1][tid] * w1 +
                  lds_ctx[2][tid] * w2 + lds_ctx[3][tid] * w3;
    *(v4f*)&part_ctx[(size_t)blk * H_ + tid * 4] = o;

    if (tid == 0) {
        const float L = lds_l[0] * w0 + lds_l[1] * w1 + lds_l[2] * w2 + lds_l[3] * w3;
        part_ml[blk * 2]     = M;
        part_ml[blk * 2 + 1] = L;
    }
}

// Pass 2: combine NBLK partials per batch; write context; normalize the
// raw scores in d_out into attn (in place). grid = (B, 5):
// y==0 -> context; y in 1..4 -> attn quarter-chunks of 1024.
__global__ __launch_bounds__(256) void attn_pass2(
    const float* __restrict__ part_ctx,  // [B*NBLK, H]
    const float* __restrict__ part_ml,   // [B*NBLK, 2]
    float* __restrict__ out_ctx,         // [B,H]
    float* __restrict__ attn)            // [B,S], holds raw scores on entry
{
    const int b    = blockIdx.x;
    const int part = blockIdx.y;
    const int tid  = threadIdx.x;

    float M = -INFINITY;
    #pragma unroll
    for (int p = 0; p < NBLK; ++p)
        M = fmaxf(M, part_ml[(b * NBLK + p) * 2]);

    float L = 0.0f;
    float w[NBLK];
    #pragma unroll
    for (int p = 0; p < NBLK; ++p) {
        w[p] = __expf(part_ml[(b * NBLK + p) * 2] - M);
        L += part_ml[(b * NBLK + p) * 2 + 1] * w[p];
    }
    const float invL = 1.0f / L;

    if (part == 0) {
        const int e = tid * 4;
        v4f acc = (v4f)0.0f;
        #pragma unroll
        for (int p = 0; p < NBLK; ++p) {
            const v4f v = *(const v4f*)&part_ctx[(size_t)(b * NBLK + p) * H_ + e];
            acc += v * w[p];
        }
        acc *= invL;
        *(v4f*)&out_ctx[(size_t)b * H_ + e] = acc;
    } else {
        const size_t s0 = (size_t)b * S_ + (size_t)(part - 1) * 1024 + tid * 4;
        v4f sc = *(const v4f*)&attn[s0];
        sc.x = __expf(sc.x - M) * invL;
        sc.y = __expf(sc.y - M) * invL;
        sc.z = __expf(sc.z - M) * invL;
        sc.w = __expf(sc.w - M) * invL;
        *(v4f*)&attn[s0] = sc;
    }
}

extern "C" void kernel_launch(void* const* d_in, const int* in_sizes, int n_in,
                              void* d_out, int out_size, void* d_ws, size_t ws_size,
                              hipStream_t stream) {
    (void)in_sizes; (void)n_in; (void)out_size; (void)ws_size;
    const float* hidden = (const float*)d_in[0];  // [2,B,H]
    const float* enc    = (const float*)d_in[1];  // [B,S,H]
    const int*   mask   = (const int*)d_in[2];    // [B,S]

    float* out      = (float*)d_out;
    float* out_ctx  = out;                        // [B,H]
    float* attn     = out + (size_t)B_ * H_;      // [B,S]

    float* part_ctx = (float*)d_ws;                        // B*NBLK*H floats (4 MB)
    float* part_ml  = part_ctx + (size_t)B_ * NBLK * H_;   // B*NBLK*2 floats

    attn_pass1<<<dim3(B_ * NBLK), dim3(256), 0, stream>>>(
        hidden, enc, mask, attn, part_ctx, part_ml);
    attn_pass2<<<dim3(B_, 5), dim3(256), 0, stream>>>(
        part_ctx, part_ml, out_ctx, attn);
}